// Round 1
// baseline (273.896 us; speedup 1.0000x reference)
//
#include <hip/hip_runtime.h>

#define SEQ    2048
#define NHEAD  16
#define HDIM   64
#define DMODEL 1024
#define BATCH  2

typedef __bf16 bf16;
typedef __bf16 bf16x8 __attribute__((ext_vector_type(8)));
typedef __bf16 bf16x4v __attribute__((ext_vector_type(4)));
typedef float  f32x4  __attribute__((ext_vector_type(4)));

typedef const __attribute__((address_space(1))) void* gas_ptr;
typedef __attribute__((address_space(3))) void*       las_ptr;

__device__ __forceinline__ f32x4 mfma16(bf16x8 a, bf16x8 b, f32x4 c) {
  return __builtin_amdgcn_mfma_f32_16x16x32_bf16(a, b, c, 0, 0, 0);
}

__device__ __forceinline__ void gload_lds16(const void* g, void* l) {
  __builtin_amdgcn_global_load_lds((gas_ptr)(unsigned long long)g,
                                   (las_ptr)(unsigned long long)l, 16, 0, 0);
}

// ---------------- fp32 -> bf16 conversion (x | w_qkv | w_proj concatenated) ----
__global__ void convert_all(const float* __restrict__ x, const float* __restrict__ wq,
                            const float* __restrict__ wp, bf16* __restrict__ out) {
  const long long NX = 4194304, NQ = 3145728, NP = 1048576;
  long long i = ((long long)blockIdx.x * blockDim.x + threadIdx.x) * 4;
  if (i >= NX + NQ + NP) return;
  const float* src; long long off;
  if (i < NX)           { src = x;  off = i; }
  else if (i < NX + NQ) { src = wq; off = i - NX; }
  else                  { src = wp; off = i - NX - NQ; }
  float4 f = *reinterpret_cast<const float4*>(src + off);
  bf16x4v r;
  r[0] = (bf16)f.x; r[1] = (bf16)f.y; r[2] = (bf16)f.z; r[3] = (bf16)f.w;
  *reinterpret_cast<bf16x4v*>(out + i) = r;
}

// ---------------- GEMM C = A(M,K) * B(N,K)^T, bf16 in, fp32 acc ---------------
// EPI 0: qkv scatter epilogue (Q scaled by 0.125). EPI 1: proj + bias, fp32 out.
template <int EPI>
__global__ __launch_bounds__(256) void gemm_bt(
    const bf16* __restrict__ A, const bf16* __restrict__ B, int K,
    bf16* __restrict__ q, bf16* __restrict__ k, bf16* __restrict__ v,
    const float* __restrict__ bias, float* __restrict__ out) {
  __shared__ alignas(16) bf16 As[2][128 * 32];
  __shared__ alignas(16) bf16 Bs[2][128 * 32];

  const int tid = threadIdx.x;
  const int l = tid & 63, w = tid >> 6;
  const int lr = l & 15, lg = l >> 4;
  const int wr = (w >> 1) * 64, wc = (w & 1) * 64;
  const long long m0 = (long long)blockIdx.x * 128;
  const long long n0 = (long long)blockIdx.y * 128;
  const int crow = tid >> 2, ccol = (tid & 3) * 8;

  auto stage = [&](int kt, int buf) {
    const bf16* a_src = A + (m0 + crow) * K + (long long)kt * 32 + ccol;
    const bf16* b_src = B + (n0 + crow) * K + (long long)kt * 32 + ccol;
    gload_lds16(a_src,           &As[buf][tid * 8]);
    gload_lds16(a_src + 64LL * K, &As[buf][(tid + 256) * 8]);
    gload_lds16(b_src,           &Bs[buf][tid * 8]);
    gload_lds16(b_src + 64LL * K, &Bs[buf][(tid + 256) * 8]);
  };

  f32x4 acc[4][4];
  const f32x4 fz = {0.f, 0.f, 0.f, 0.f};
#pragma unroll
  for (int m = 0; m < 4; ++m)
#pragma unroll
    for (int n = 0; n < 4; ++n) acc[m][n] = fz;

  stage(0, 0);
  const int nk = K >> 5;
  int cur = 0;
  for (int kt = 0; kt < nk; ++kt) {
    __syncthreads();  // drains vmcnt: buf[cur] staged; prev compute done
    if (kt + 1 < nk) stage(kt + 1, cur ^ 1);
    bf16x8 af[4], bfv[4];
#pragma unroll
    for (int m = 0; m < 4; ++m)
      af[m] = *reinterpret_cast<const bf16x8*>(&As[cur][(wr + m * 16 + lr) * 32 + lg * 8]);
#pragma unroll
    for (int n = 0; n < 4; ++n)
      bfv[n] = *reinterpret_cast<const bf16x8*>(&Bs[cur][(wc + n * 16 + lr) * 32 + lg * 8]);
#pragma unroll
    for (int m = 0; m < 4; ++m)
#pragma unroll
      for (int n = 0; n < 4; ++n) acc[m][n] = mfma16(af[m], bfv[n], acc[m][n]);
    cur ^= 1;
  }

#pragma unroll
  for (int m = 0; m < 4; ++m) {
#pragma unroll
    for (int n = 0; n < 4; ++n) {
#pragma unroll
      for (int j = 0; j < 4; ++j) {
        long long grow = m0 + wr + m * 16 + lg * 4 + j;   // row in (B*S)
        long long gcol = n0 + wc + n * 16 + lr;           // col in N
        float val = acc[m][n][j];
        if (EPI == 0) {
          int three = (int)(gcol >> 10);
          int rem = (int)(gcol & 1023);
          int h = rem >> 6, d = rem & 63;
          long long bb = grow >> 11, s = grow & 2047;
          long long dst = (((bb * NHEAD + h) * SEQ) + s) * HDIM + d;
          if (three == 0)      q[dst] = (bf16)(val * 0.125f);   // pre-scale Q
          else if (three == 1) k[dst] = (bf16)val;
          else                 v[dst] = (bf16)val;
        } else {
          out[grow * 1024 + gcol] = val + bias[gcol];
        }
      }
    }
  }
}

// ---------------- causal flash attention, bf16, hd=64 -------------------------
// grid (32 q-tiles, 32 bh). 4 waves/block; wave w owns 16 q-rows.
__global__ __launch_bounds__(256) void attn_kernel(
    const bf16* __restrict__ qbuf, const bf16* __restrict__ kbuf,
    const bf16* __restrict__ vbuf, bf16* __restrict__ ctx) {
  const int qt = blockIdx.x;
  const int bh = blockIdx.y;
  const int tid = threadIdx.x;
  const int l = tid & 63, w = tid >> 6;
  const int lr = l & 15, lg = l >> 4;

  __shared__ alignas(16) bf16 Vt[64][72];      // V transposed: Vt[d][k], pad->2-way free
  __shared__ alignas(16) bf16 Pl[4][16][72];   // per-wave P staging

  const bf16* Qb = qbuf + (long long)bh * SEQ * HDIM;
  const bf16* Kb = kbuf + (long long)bh * SEQ * HDIM;
  const bf16* Vb = vbuf + (long long)bh * SEQ * HDIM;

  const int qrow0 = qt * 64 + w * 16;
  bf16x8 qf[2];
  qf[0] = *reinterpret_cast<const bf16x8*>(&Qb[(long long)(qrow0 + lr) * 64 + lg * 8]);
  qf[1] = *reinterpret_cast<const bf16x8*>(&Qb[(long long)(qrow0 + lr) * 64 + 32 + lg * 8]);

  const f32x4 fz = {0.f, 0.f, 0.f, 0.f};
  f32x4 o[4];
  float mrow[4], lrow[4];
#pragma unroll
  for (int nd = 0; nd < 4; ++nd) o[nd] = fz;
#pragma unroll
  for (int j = 0; j < 4; ++j) { mrow[j] = -1e30f; lrow[j] = 0.f; }

  for (int kt = 0; kt <= qt; ++kt) {
    __syncthreads();  // protect Vt from previous iteration's PV reads
    // stage V^T: thread reads 16B of a V row, writes a column of Vt
#pragma unroll
    for (int r = 0; r < 2; ++r) {
      int c = r * 256 + tid;
      int row = c >> 3, col = (c & 7) * 8;
      bf16x8 vv = *reinterpret_cast<const bf16x8*>(&Vb[(long long)(kt * 64 + row) * 64 + col]);
#pragma unroll
      for (int e = 0; e < 8; ++e) Vt[col + e][row] = vv[e];
    }
    // QK^T: K fragments direct from global (L2-resident)
    f32x4 s[4];
#pragma unroll
    for (int n = 0; n < 4; ++n) s[n] = fz;
#pragma unroll
    for (int n = 0; n < 4; ++n)
#pragma unroll
      for (int kk = 0; kk < 2; ++kk) {
        bf16x8 kf = *reinterpret_cast<const bf16x8*>(
            &Kb[(long long)(kt * 64 + n * 16 + lr) * 64 + kk * 32 + lg * 8]);
        s[n] = mfma16(qf[kk], kf, s[n]);
      }
    if (kt == qt) {  // causal mask on diagonal tile
#pragma unroll
      for (int n = 0; n < 4; ++n)
#pragma unroll
        for (int j = 0; j < 4; ++j)
          if (n * 16 + lr > w * 16 + lg * 4 + j) s[n][j] = -1e30f;
    }
    // online softmax (row r = lg*4+j lives on the 16 lanes sharing lg)
    float pm[4];
#pragma unroll
    for (int j = 0; j < 4; ++j)
      pm[j] = fmaxf(fmaxf(s[0][j], s[1][j]), fmaxf(s[2][j], s[3][j]));
#pragma unroll
    for (int msk = 1; msk <= 8; msk <<= 1)
#pragma unroll
      for (int j = 0; j < 4; ++j) pm[j] = fmaxf(pm[j], __shfl_xor(pm[j], msk, 64));
    float alpha[4], rs[4];
#pragma unroll
    for (int j = 0; j < 4; ++j) {
      float mn = fmaxf(mrow[j], pm[j]);
      alpha[j] = __expf(mrow[j] - mn);
      mrow[j] = mn;
      rs[j] = 0.f;
    }
#pragma unroll
    for (int n = 0; n < 4; ++n)
#pragma unroll
      for (int j = 0; j < 4; ++j) {
        float p = __expf(s[n][j] - mrow[j]);
        s[n][j] = p;
        rs[j] += p;
      }
#pragma unroll
    for (int msk = 1; msk <= 8; msk <<= 1)
#pragma unroll
      for (int j = 0; j < 4; ++j) rs[j] += __shfl_xor(rs[j], msk, 64);
#pragma unroll
    for (int j = 0; j < 4; ++j) lrow[j] = lrow[j] * alpha[j] + rs[j];
#pragma unroll
    for (int nd = 0; nd < 4; ++nd)
#pragma unroll
      for (int j = 0; j < 4; ++j) o[nd][j] *= alpha[j];
    // P -> LDS (bf16) for the PV A-operand
#pragma unroll
    for (int n = 0; n < 4; ++n)
#pragma unroll
      for (int j = 0; j < 4; ++j)
        Pl[w][lg * 4 + j][n * 16 + lr] = (bf16)s[n][j];
    __syncthreads();  // Vt staged & visible
    // PV
#pragma unroll
    for (int kk = 0; kk < 2; ++kk) {
      bf16x8 pf = *reinterpret_cast<const bf16x8*>(&Pl[w][lr][kk * 32 + lg * 8]);
#pragma unroll
      for (int nd = 0; nd < 4; ++nd) {
        bf16x8 vf = *reinterpret_cast<const bf16x8*>(&Vt[nd * 16 + lr][kk * 32 + lg * 8]);
        o[nd] = mfma16(pf, vf, o[nd]);
      }
    }
  }

  float inv[4];
#pragma unroll
  for (int j = 0; j < 4; ++j) inv[j] = 1.0f / lrow[j];
  const int b = bh >> 4, h = bh & 15;
#pragma unroll
  for (int nd = 0; nd < 4; ++nd)
#pragma unroll
    for (int j = 0; j < 4; ++j) {
      int srow = qrow0 + lg * 4 + j;
      int d = nd * 16 + lr;
      ctx[((long long)(b * SEQ + srow)) * DMODEL + h * HDIM + d] = (bf16)(o[nd][j] * inv[j]);
    }
}

extern "C" void kernel_launch(void* const* d_in, const int* in_sizes, int n_in,
                              void* d_out, int out_size, void* d_ws, size_t ws_size,
                              hipStream_t stream) {
  const float* x      = (const float*)d_in[0];
  const float* w_qkv  = (const float*)d_in[1];
  const float* w_proj = (const float*)d_in[2];
  const float* b_proj = (const float*)d_in[3];
  float* out = (float*)d_out;

  bf16* ws = (bf16*)d_ws;
  bf16* xb     = ws;                   // 4194304 elems
  bf16* wqkvb  = xb + 4194304;         // 3145728
  bf16* wprojb = wqkvb + 3145728;      // 1048576
  bf16* qb     = wprojb + 1048576;     // 4194304 (Q, pre-scaled)
  bf16* kb     = qb + 4194304;         // 4194304
  bf16* vb     = kb + 4194304;         // 4194304
  bf16* ctxb   = vb + 4194304;         // 4194304   total ~48 MB

  convert_all<<<8192, 256, 0, stream>>>(x, w_qkv, w_proj, xb);
  gemm_bt<0><<<dim3(32, 24), 256, 0, stream>>>(xb, wqkvb, 1024, qb, kb, vb, nullptr, nullptr);
  attn_kernel<<<dim3(32, 32), 256, 0, stream>>>(qb, kb, vb, ctxb);
  gemm_bt<1><<<dim3(32, 8), 256, 0, stream>>>(ctxb, wprojb, 1024, nullptr, nullptr, nullptr,
                                              b_proj, out);
}

// Round 2
// 245.136 us; speedup vs baseline: 1.1173x; 1.1173x over previous
//
#include <hip/hip_runtime.h>

#define SEQ    2048
#define NHEAD  16
#define HDIM   64
#define DMODEL 1024
#define BATCH  2

typedef __bf16 bf16;
typedef __bf16 bf16x8 __attribute__((ext_vector_type(8)));
typedef __bf16 bf16x4v __attribute__((ext_vector_type(4)));
typedef float  f32x4  __attribute__((ext_vector_type(4)));

typedef const __attribute__((address_space(1))) void* gas_ptr;
typedef __attribute__((address_space(3))) void*       las_ptr;

__device__ __forceinline__ f32x4 mfma16(bf16x8 a, bf16x8 b, f32x4 c) {
  return __builtin_amdgcn_mfma_f32_16x16x32_bf16(a, b, c, 0, 0, 0);
}

__device__ __forceinline__ void gload_lds16(const void* g, void* l) {
  __builtin_amdgcn_global_load_lds((gas_ptr)(unsigned long long)g,
                                   (las_ptr)(unsigned long long)l, 16, 0, 0);
}

// ---------------- fp32 -> bf16 conversion (x | w_qkv | w_proj concatenated) ----
__global__ void convert_all(const float* __restrict__ x, const float* __restrict__ wq,
                            const float* __restrict__ wp, bf16* __restrict__ out) {
  const long long NX = 4194304, NQ = 3145728, NP = 1048576;
  long long i = ((long long)blockIdx.x * blockDim.x + threadIdx.x) * 4;
  if (i >= NX + NQ + NP) return;
  const float* src; long long off;
  if (i < NX)           { src = x;  off = i; }
  else if (i < NX + NQ) { src = wq; off = i - NX; }
  else                  { src = wp; off = i - NX - NQ; }
  float4 f = *reinterpret_cast<const float4*>(src + off);
  bf16x4v r;
  r[0] = (bf16)f.x; r[1] = (bf16)f.y; r[2] = (bf16)f.z; r[3] = (bf16)f.w;
  *reinterpret_cast<bf16x4v*>(out + i) = r;
}

// ---------------- GEMM C = A(M,K) * B(N,K)^T, bf16 in, fp32 acc ---------------
// EPI 0: qkv scatter epilogue (Q scaled by 0.125). EPI 1: proj + bias, fp32 out.
template <int EPI>
__global__ __launch_bounds__(256) void gemm_bt(
    const bf16* __restrict__ A, const bf16* __restrict__ B, int K,
    bf16* __restrict__ q, bf16* __restrict__ k, bf16* __restrict__ v,
    const float* __restrict__ bias, float* __restrict__ out) {
  __shared__ alignas(16) bf16 As[2][128 * 32];
  __shared__ alignas(16) bf16 Bs[2][128 * 32];

  const int tid = threadIdx.x;
  const int l = tid & 63, w = tid >> 6;
  const int lr = l & 15, lg = l >> 4;
  const int wr = (w >> 1) * 64, wc = (w & 1) * 64;
  const long long m0 = (long long)blockIdx.x * 128;
  const long long n0 = (long long)blockIdx.y * 128;
  const int crow = tid >> 2, ccol = (tid & 3) * 8;

  auto stage = [&](int kt, int buf) {
    const bf16* a_src = A + (m0 + crow) * K + (long long)kt * 32 + ccol;
    const bf16* b_src = B + (n0 + crow) * K + (long long)kt * 32 + ccol;
    gload_lds16(a_src,           &As[buf][tid * 8]);
    gload_lds16(a_src + 64LL * K, &As[buf][(tid + 256) * 8]);
    gload_lds16(b_src,           &Bs[buf][tid * 8]);
    gload_lds16(b_src + 64LL * K, &Bs[buf][(tid + 256) * 8]);
  };

  f32x4 acc[4][4];
  const f32x4 fz = {0.f, 0.f, 0.f, 0.f};
#pragma unroll
  for (int m = 0; m < 4; ++m)
#pragma unroll
    for (int n = 0; n < 4; ++n) acc[m][n] = fz;

  stage(0, 0);
  const int nk = K >> 5;
  int cur = 0;
  for (int kt = 0; kt < nk; ++kt) {
    __syncthreads();  // drains vmcnt: buf[cur] staged; prev compute done
    if (kt + 1 < nk) stage(kt + 1, cur ^ 1);
    bf16x8 af[4], bfv[4];
#pragma unroll
    for (int m = 0; m < 4; ++m)
      af[m] = *reinterpret_cast<const bf16x8*>(&As[cur][(wr + m * 16 + lr) * 32 + lg * 8]);
#pragma unroll
    for (int n = 0; n < 4; ++n)
      bfv[n] = *reinterpret_cast<const bf16x8*>(&Bs[cur][(wc + n * 16 + lr) * 32 + lg * 8]);
#pragma unroll
    for (int m = 0; m < 4; ++m)
#pragma unroll
      for (int n = 0; n < 4; ++n) acc[m][n] = mfma16(af[m], bfv[n], acc[m][n]);
    cur ^= 1;
  }

#pragma unroll
  for (int m = 0; m < 4; ++m) {
#pragma unroll
    for (int n = 0; n < 4; ++n) {
#pragma unroll
      for (int j = 0; j < 4; ++j) {
        long long grow = m0 + wr + m * 16 + lg * 4 + j;   // row in (B*S)
        long long gcol = n0 + wc + n * 16 + lr;           // col in N
        float val = acc[m][n][j];
        if (EPI == 0) {
          int three = (int)(gcol >> 10);
          int rem = (int)(gcol & 1023);
          int h = rem >> 6, d = rem & 63;
          long long bb = grow >> 11, s = grow & 2047;
          long long dst = (((bb * NHEAD + h) * SEQ) + s) * HDIM + d;
          if (three == 0)      q[dst] = (bf16)(val * 0.125f);   // pre-scale Q
          else if (three == 1) k[dst] = (bf16)val;
          else                 v[dst] = (bf16)val;
        } else {
          out[grow * 1024 + gcol] = val + bias[gcol];
        }
      }
    }
  }
}

// ---------------- causal flash attention, bf16, hd=64 -------------------------
// grid (16 q-tile PAIRS, 32 bh). Block handles q-tiles {p, 31-p} sequentially:
// uniform 33 iterations -> no causal load imbalance. 4 waves; wave owns 16 q-rows.
// Vt double-buffered + XOR-swizzled (chunk k' = (k>>3)^(d&7)): conflict-free
// staging writes (wave-uniform d row) and conflict-free ds_read_b128 in PV.
// One __syncthreads per iteration; V prefetched to regs one iter ahead (T14).
__global__ __launch_bounds__(256) void attn_kernel(
    const bf16* __restrict__ qbuf, const bf16* __restrict__ kbuf,
    const bf16* __restrict__ vbuf, bf16* __restrict__ ctx) {
  const int pidx = blockIdx.x;
  const int bh = blockIdx.y;
  const int tid = threadIdx.x;
  const int l = tid & 63, w = tid >> 6;
  const int lr = l & 15, lg = l >> 4;

  __shared__ alignas(16) bf16 Vt[2][64 * 64];   // swizzled V^T: [d][(k>>3)^(d&7) | k&7]
  __shared__ alignas(16) bf16 Pl[4][16][68];    // row stride 68 (34 dw ≡ 2 mod 32): 2-way free

  const bf16* Qb = qbuf + (long long)bh * SEQ * HDIM;
  const bf16* Kb = kbuf + (long long)bh * SEQ * HDIM;
  const bf16* Vb = vbuf + (long long)bh * SEQ * HDIM;

  const int qa = pidx, qb_t = 31 - pidx;        // pair of q-tiles, qa < qb_t

  // V staging mapping: key = lane (64 rows), dbase = (r*4 + w)*8.
  // global read: V[key][dbase..dbase+7]; write: row d=dbase+e of Vt, byte k*2
  // (contiguous 128B per wave-instr, XOR uniform) -> conflict-free both sides.
  const int vkey = l;

  const f32x4 fz = {0.f, 0.f, 0.f, 0.f};
  f32x4 o[4];
  float mrow[4], lrow[4];
  bf16x8 qf[2];
  bf16x8 vv[2];

  // prologue prefetch: V tile kt=0 (for q-tile qa)
#pragma unroll
  for (int r = 0; r < 2; ++r) {
    int dbase = (r * 4 + w) * 8;
    vv[r] = *reinterpret_cast<const bf16x8*>(&Vb[(long long)vkey * 64 + dbase]);
  }

  const int total = qa + qb_t + 2;  // 33
  for (int i = 0; i < total; ++i) {
    const int in_a = (i <= qa);
    const int qt = in_a ? qa : qb_t;
    const int kt = in_a ? i : i - qa - 1;
    const int buf = i & 1;

    if (kt == 0) {  // new q-tile: load Q frags, reset state
      const int qrow0 = qt * 64 + w * 16;
      qf[0] = *reinterpret_cast<const bf16x8*>(&Qb[(long long)(qrow0 + lr) * 64 + lg * 8]);
      qf[1] = *reinterpret_cast<const bf16x8*>(&Qb[(long long)(qrow0 + lr) * 64 + 32 + lg * 8]);
#pragma unroll
      for (int nd = 0; nd < 4; ++nd) o[nd] = fz;
#pragma unroll
      for (int j = 0; j < 4; ++j) { mrow[j] = -1e30f; lrow[j] = 0.f; }
    }

    // write prefetched V regs -> Vt[buf] (swizzled)
#pragma unroll
    for (int r = 0; r < 2; ++r) {
      int dbase = (r * 4 + w) * 8;
#pragma unroll
      for (int e = 0; e < 8; ++e) {
        int d = dbase + e;
        Vt[buf][d * 64 + (((vkey >> 3) ^ e) << 3) + (vkey & 7)] = vv[r][e];
      }
    }
    // issue prefetch for next iteration's V tile
    if (i + 1 < total) {
      const int kt2 = (i + 1 <= qa) ? i + 1 : i - qa;
      const bf16* vsrc = Vb + (long long)(kt2 * 64 + vkey) * 64;
#pragma unroll
      for (int r = 0; r < 2; ++r)
        vv[r] = *reinterpret_cast<const bf16x8*>(&vsrc[(r * 4 + w) * 8]);
    }

    // QK^T: K fragments direct from global (L2-resident)
    f32x4 s[4];
#pragma unroll
    for (int n = 0; n < 4; ++n) s[n] = fz;
    const bf16* ksrc = Kb + (long long)kt * 64 * 64;
#pragma unroll
    for (int n = 0; n < 4; ++n)
#pragma unroll
      for (int kk = 0; kk < 2; ++kk) {
        bf16x8 kf = *reinterpret_cast<const bf16x8*>(
            &ksrc[(long long)(n * 16 + lr) * 64 + kk * 32 + lg * 8]);
        s[n] = mfma16(qf[kk], kf, s[n]);
      }
    if (kt == qt) {  // causal mask on diagonal tile
#pragma unroll
      for (int n = 0; n < 4; ++n)
#pragma unroll
        for (int j = 0; j < 4; ++j)
          if (n * 16 + lr > w * 16 + lg * 4 + j) s[n][j] = -1e30f;
    }

    // online softmax (row r = lg*4+j lives on the 16 lanes sharing lg)
    float pm[4];
#pragma unroll
    for (int j = 0; j < 4; ++j)
      pm[j] = fmaxf(fmaxf(s[0][j], s[1][j]), fmaxf(s[2][j], s[3][j]));
#pragma unroll
    for (int msk = 1; msk <= 8; msk <<= 1)
#pragma unroll
      for (int j = 0; j < 4; ++j) pm[j] = fmaxf(pm[j], __shfl_xor(pm[j], msk, 64));
    float alpha[4], rs[4];
#pragma unroll
    for (int j = 0; j < 4; ++j) {
      float mn = fmaxf(mrow[j], pm[j]);
      alpha[j] = __expf(mrow[j] - mn);
      mrow[j] = mn;
      rs[j] = 0.f;
    }
#pragma unroll
    for (int n = 0; n < 4; ++n)
#pragma unroll
      for (int j = 0; j < 4; ++j) {
        float p = __expf(s[n][j] - mrow[j]);
        s[n][j] = p;
        rs[j] += p;
      }
#pragma unroll
    for (int msk = 1; msk <= 8; msk <<= 1)
#pragma unroll
      for (int j = 0; j < 4; ++j) rs[j] += __shfl_xor(rs[j], msk, 64);
#pragma unroll
    for (int j = 0; j < 4; ++j) lrow[j] = lrow[j] * alpha[j] + rs[j];
#pragma unroll
    for (int nd = 0; nd < 4; ++nd)
#pragma unroll
      for (int j = 0; j < 4; ++j) o[nd][j] *= alpha[j];

    // P -> LDS (per-wave private; no barrier needed for Pl)
#pragma unroll
    for (int n = 0; n < 4; ++n)
#pragma unroll
      for (int j = 0; j < 4; ++j)
        Pl[w][lg * 4 + j][n * 16 + lr] = (bf16)s[n][j];

    __syncthreads();  // Vt[buf] staged by all waves; also fences prev-buf reuse

    // PV: A = P (from Pl), B = V^T (swizzled Vt)
#pragma unroll
    for (int kk = 0; kk < 2; ++kk) {
      bf16x8 pf = *reinterpret_cast<const bf16x8*>(&Pl[w][lr][kk * 32 + lg * 8]);
#pragma unroll
      for (int nd = 0; nd < 4; ++nd) {
        int d = nd * 16 + lr;
        bf16x8 vf = *reinterpret_cast<const bf16x8*>(
            &Vt[buf][d * 64 + ((((kk * 4) + lg) ^ (d & 7)) << 3)]);
        o[nd] = mfma16(pf, vf, o[nd]);
      }
    }

    if (kt == qt) {  // q-tile finished: normalize and write out
      float inv[4];
#pragma unroll
      for (int j = 0; j < 4; ++j) inv[j] = 1.0f / lrow[j];
      const int b = bh >> 4, h = bh & 15;
      const int qrow0 = qt * 64 + w * 16;
#pragma unroll
      for (int nd = 0; nd < 4; ++nd)
#pragma unroll
        for (int j = 0; j < 4; ++j) {
          int srow = qrow0 + lg * 4 + j;
          int d = nd * 16 + lr;
          ctx[((long long)(b * SEQ + srow)) * DMODEL + h * HDIM + d] =
              (bf16)(o[nd][j] * inv[j]);
        }
    }
  }
}

extern "C" void kernel_launch(void* const* d_in, const int* in_sizes, int n_in,
                              void* d_out, int out_size, void* d_ws, size_t ws_size,
                              hipStream_t stream) {
  const float* x      = (const float*)d_in[0];
  const float* w_qkv  = (const float*)d_in[1];
  const float* w_proj = (const float*)d_in[2];
  const float* b_proj = (const float*)d_in[3];
  float* out = (float*)d_out;

  bf16* ws = (bf16*)d_ws;
  bf16* xb     = ws;                   // 4194304 elems
  bf16* wqkvb  = xb + 4194304;         // 3145728
  bf16* wprojb = wqkvb + 3145728;      // 1048576
  bf16* qb     = wprojb + 1048576;     // 4194304 (Q, pre-scaled)
  bf16* kb     = qb + 4194304;         // 4194304
  bf16* vb     = kb + 4194304;         // 4194304
  bf16* ctxb   = vb + 4194304;         // 4194304   total ~48 MB

  convert_all<<<8192, 256, 0, stream>>>(x, w_qkv, w_proj, xb);
  gemm_bt<0><<<dim3(32, 24), 256, 0, stream>>>(xb, wqkvb, 1024, qb, kb, vb, nullptr, nullptr);
  attn_kernel<<<dim3(16, 32), 256, 0, stream>>>(qb, kb, vb, ctxb);
  gemm_bt<1><<<dim3(32, 8), 256, 0, stream>>>(ctxb, wprojb, 1024, nullptr, nullptr, nullptr,
                                              b_proj, out);
}